// Round 4
// baseline (273.691 us; speedup 1.0000x reference)
//
#include <hip/hip_runtime.h>
#include <hip/hip_bf16.h>
#include <cstdint>
#include <cstddef>

#define C_CH 128
#define L_LEN 16384
#define B_N 8
#define K_T 3
#define EPS 1e-5f
#define WPAD 8
#define WIN_O 144    // kernel O window rows (128-l tile + 2*8)
#define WIN_G 80     // kernel G window rows (64-l tile + 2*8)

typedef __attribute__((ext_vector_type(8))) short short8;
typedef __attribute__((ext_vector_type(4))) float float4v;

__device__ __forceinline__ short f2bf(float f) {
  union { float f; unsigned u; } v; v.f = f;
  unsigned r = v.u + 0x7fffu + ((v.u >> 16) & 1u);
  return (short)(r >> 16);
}
__device__ __forceinline__ float bflo(unsigned d) {
  union { unsigned u; float f; } v; v.u = d << 16; return v.f;
}
__device__ __forceinline__ float bfhi(unsigned d) {
  union { unsigned u; float f; } v; v.u = d & 0xffff0000u; return v.f;
}
__device__ __forceinline__ unsigned packbf(float a, float b) {
  unsigned ua = __float_as_uint(a) + 0x8000u;
  unsigned ub = __float_as_uint(b) + 0x8000u;
  return (ua >> 16) | (ub & 0xffff0000u);
}
__device__ __forceinline__ int clampL(int v) {
  return v < 0 ? 0 : (v > L_LEN - 1 ? L_LEN - 1 : v);
}

// ---- repack dc_w [m][c][kt] f32 -> Wp2, linear = ((ks*4+qk)*128 + m)*8 + j,
// element = A[m][k = ks*32 + qk*8 + j] = dcw[m][c][kt], c = qk*32 + s*8 + j, kt=ks>>2, s=ks&3.
__global__ void repack_w2(const float* __restrict__ dc_w, short* __restrict__ Wp2) {
  int tid = blockIdx.x * 256 + threadIdx.x;
  if (tid >= C_CH * C_CH * K_T) return;
  int j = tid & 7;
  int m = (tid >> 3) & 127;
  int qk = (tid >> 10) & 3;
  int ks = tid >> 12;            // 0..11
  int kt = ks >> 2, s = ks & 3;
  int c = qk * 32 + s * 8 + j;
  Wp2[tid] = f2bf(dc_w[(m * C_CH + c) * K_T + kt]);
}

// ---- Kernel O: stage x window -> dwconv + LN + ReLU + offset linear -> interp descriptors.
// desc: d_wa/d_wb [b][tap][l] f32 (weights, zeroed when ref tap invalid), d_idx = i0c | i1c<<16 (global, clamped).
__global__ __launch_bounds__(512, 4) void offsets_k2(
    const float* __restrict__ x,
    const float* __restrict__ dw_w, const float* __restrict__ dw_b,
    const float* __restrict__ ln_g, const float* __restrict__ ln_b,
    const float* __restrict__ off_w, const float* __restrict__ off_b,
    float* __restrict__ d_wa, float* __restrict__ d_wb, unsigned* __restrict__ d_idx) {
  __shared__ uint4 xs4[WIN_O * 16];     // 36864 B, row r: 16 chunks of 16 B, chunk ch at (ch ^ (r&15))
  char* xsb = (char*)xs4;
  int t = threadIdx.x;
  int b = blockIdx.y;
  int l0 = blockIdx.x * 128;
  int wb0 = l0 - WPAD;
  const float* xb = x + (size_t)b * C_CH * L_LEN;

  // stage: pass 1 rows 0..127 (4 chunks/thread), pass 2 rows 128..143 (256 threads, 1 chunk)
  {
    int r = t & 127, cg = t >> 7;       // cg 0..3
    int lg = clampL(wb0 + r);
    #pragma unroll
    for (int k = 0; k < 4; ++k) {
      int ch = cg * 4 + k;
      uint4 q;
      unsigned* qu = (unsigned*)&q;
      #pragma unroll
      for (int i = 0; i < 4; ++i) {
        int c = ch * 8 + 2 * i;
        qu[i] = packbf(xb[(size_t)c * L_LEN + lg], xb[(size_t)(c + 1) * L_LEN + lg]);
      }
      *(uint4*)(xsb + r * 256 + ((ch ^ (r & 15)) << 4)) = q;
    }
  }
  if (t < 256) {
    int r = 128 + (t & 15), ch = t >> 4;
    int lg = clampL(wb0 + r);
    uint4 q;
    unsigned* qu = (unsigned*)&q;
    #pragma unroll
    for (int i = 0; i < 4; ++i) {
      int c = ch * 8 + 2 * i;
      qu[i] = packbf(xb[(size_t)c * L_LEN + lg], xb[(size_t)(c + 1) * L_LEN + lg]);
    }
    *(uint4*)(xsb + r * 256 + ((ch ^ (r & 15)) << 4)) = q;
  }
  __syncthreads();

  // offsets: 4 threads per l
  int l_loc = t >> 2, sub = t & 3;
  int lg = l0 + l_loc;
  float mL = (lg >= 1) ? 1.f : 0.f;
  float mR = (lg + 1 < L_LEN) ? 1.f : 0.f;
  int r0 = l_loc + 7, r1 = l_loc + 8, r2 = l_loc + 9;

  float sum = 0.f, sumsq = 0.f;
  #pragma unroll
  for (int oct = 0; oct < 4; ++oct) {
    int ch = sub * 4 + oct;
    int cb = ch * 8;
    uint4 q0 = *(const uint4*)(xsb + r0 * 256 + ((ch ^ (r0 & 15)) << 4));
    uint4 q1 = *(const uint4*)(xsb + r1 * 256 + ((ch ^ (r1 & 15)) << 4));
    uint4 q2 = *(const uint4*)(xsb + r2 * 256 + ((ch ^ (r2 & 15)) << 4));
    const unsigned* u0 = (const unsigned*)&q0;
    const unsigned* u1 = (const unsigned*)&q1;
    const unsigned* u2 = (const unsigned*)&q2;
    #pragma unroll
    for (int j = 0; j < 4; ++j) {
      int c = cb + 2 * j;
      float y0 = dw_b[c] + mL * bflo(u0[j]) * dw_w[c * 3]
               + bflo(u1[j]) * dw_w[c * 3 + 1] + mR * bflo(u2[j]) * dw_w[c * 3 + 2];
      float y1 = dw_b[c + 1] + mL * bfhi(u0[j]) * dw_w[c * 3 + 3]
               + bfhi(u1[j]) * dw_w[c * 3 + 4] + mR * bfhi(u2[j]) * dw_w[c * 3 + 5];
      sum += y0 + y1;
      sumsq += y0 * y0 + y1 * y1;
    }
  }
  sum += __shfl_xor(sum, 1, 64);   sum += __shfl_xor(sum, 2, 64);
  sumsq += __shfl_xor(sumsq, 1, 64); sumsq += __shfl_xor(sumsq, 2, 64);
  float mean = sum * (1.f / C_CH);
  float var = sumsq * (1.f / C_CH) - mean * mean;
  float rstd = rsqrtf(var + EPS);

  float o0 = 0.f, o1 = 0.f, o2 = 0.f;
  #pragma unroll
  for (int oct = 0; oct < 4; ++oct) {
    int ch = sub * 4 + oct;
    int cb = ch * 8;
    uint4 q0 = *(const uint4*)(xsb + r0 * 256 + ((ch ^ (r0 & 15)) << 4));
    uint4 q1 = *(const uint4*)(xsb + r1 * 256 + ((ch ^ (r1 & 15)) << 4));
    uint4 q2 = *(const uint4*)(xsb + r2 * 256 + ((ch ^ (r2 & 15)) << 4));
    const unsigned* u0 = (const unsigned*)&q0;
    const unsigned* u1 = (const unsigned*)&q1;
    const unsigned* u2 = (const unsigned*)&q2;
    #pragma unroll
    for (int j = 0; j < 4; ++j) {
      int c = cb + 2 * j;
      float y0 = dw_b[c] + mL * bflo(u0[j]) * dw_w[c * 3]
               + bflo(u1[j]) * dw_w[c * 3 + 1] + mR * bflo(u2[j]) * dw_w[c * 3 + 2];
      float y1 = dw_b[c + 1] + mL * bfhi(u0[j]) * dw_w[c * 3 + 3]
               + bfhi(u1[j]) * dw_w[c * 3 + 4] + mR * bfhi(u2[j]) * dw_w[c * 3 + 5];
      float yn0 = (y0 - mean) * rstd * ln_g[c] + ln_b[c];
      float yn1 = (y1 - mean) * rstd * ln_g[c + 1] + ln_b[c + 1];
      float yr0 = yn0 > 0.f ? yn0 : 0.f;
      float yr1 = yn1 > 0.f ? yn1 : 0.f;
      o0 += yr0 * off_w[c] + yr1 * off_w[c + 1];
      o1 += yr0 * off_w[C_CH + c] + yr1 * off_w[C_CH + c + 1];
      o2 += yr0 * off_w[2 * C_CH + c] + yr1 * off_w[2 * C_CH + c + 1];
    }
  }
  o0 += __shfl_xor(o0, 1, 64); o0 += __shfl_xor(o0, 2, 64);
  o1 += __shfl_xor(o1, 1, 64); o1 += __shfl_xor(o1, 2, 64);
  o2 += __shfl_xor(o2, 1, 64); o2 += __shfl_xor(o2, 2, 64);

  if (sub < 3) {
    int tap = sub;
    float o = (tap == 0 ? o0 : (tap == 1 ? o1 : o2)) + off_b[tap];
    float pos = (float)(lg + tap - 1) + o;
    float p0f = floorf(pos);
    float fr = pos - p0f;
    int i0 = (int)p0f;
    int i1 = i0 + 1;
    float wa = (i0 >= 0 && i0 < L_LEN) ? (1.f - fr) : 0.f;
    float wbv = (i1 >= 0 && i1 < L_LEN) ? fr : 0.f;
    int i0c = clampL(i0);
    int i1c = clampL(i1);
    size_t di = ((size_t)b * K_T + tap) * L_LEN + lg;
    d_wa[di] = wa;
    d_wb[di] = wbv;
    d_idx[di] = (unsigned)i0c | ((unsigned)i1c << 16);
  }
}

// ---- Kernel G: deform GEMM. Block 256 thr (4 waves), tile M=128 x N=64, wave = 16-col slice.
__global__ __launch_bounds__(256, 4) void deform_gemm2(
    const float* __restrict__ x,
    const float* __restrict__ d_wa, const float* __restrict__ d_wb,
    const unsigned* __restrict__ d_idx,
    const short* __restrict__ Wp2, float* __restrict__ out) {
  __shared__ uint4 xs4[WIN_G * 16];     // 20480 B
  __shared__ float s_wa[K_T][64];
  __shared__ float s_wb[K_T][64];
  __shared__ unsigned s_r01[K_T][64];   // r0 | r1<<8 (window-relative)

  char* xsb = (char*)xs4;
  int t = threadIdx.x;
  int b = blockIdx.y;
  int l0 = blockIdx.x * 64;
  int wb0 = l0 - WPAD;
  const float* xb = x + (size_t)b * C_CH * L_LEN;

  // stage: pass 1 rows 0..63 (wave w = chunk group w, 4 chunks/thread), pass 2 rows 64..79
  {
    int r = t & 63, cg = t >> 6;
    int lg = clampL(wb0 + r);
    #pragma unroll
    for (int k = 0; k < 4; ++k) {
      int ch = cg * 4 + k;
      uint4 q;
      unsigned* qu = (unsigned*)&q;
      #pragma unroll
      for (int i = 0; i < 4; ++i) {
        int c = ch * 8 + 2 * i;
        qu[i] = packbf(xb[(size_t)c * L_LEN + lg], xb[(size_t)(c + 1) * L_LEN + lg]);
      }
      *(uint4*)(xsb + r * 256 + ((ch ^ (r & 15)) << 4)) = q;
    }
  }
  {
    int r = 64 + (t & 15), ch = t >> 4;  // 256 tasks exactly
    int lg = clampL(wb0 + r);
    uint4 q;
    unsigned* qu = (unsigned*)&q;
    #pragma unroll
    for (int i = 0; i < 4; ++i) {
      int c = ch * 8 + 2 * i;
      qu[i] = packbf(xb[(size_t)c * L_LEN + lg], xb[(size_t)(c + 1) * L_LEN + lg]);
    }
    *(uint4*)(xsb + r * 256 + ((ch ^ (r & 15)) << 4)) = q;
  }
  // descriptors -> window-relative
  if (t < 192) {
    int n_ = t & 63, tap = t >> 6;
    int lg = l0 + n_;
    size_t di = ((size_t)b * K_T + tap) * L_LEN + lg;
    float wa = d_wa[di];
    float wbv = d_wb[di];
    unsigned ii = d_idx[di];
    int rr0 = (int)(ii & 0xffffu) - wb0;
    int rr1 = (int)(ii >> 16) - wb0;
    if ((unsigned)rr0 >= WIN_G) { rr0 = 0; wa = 0.f; }   // ~40-sigma guard
    if ((unsigned)rr1 >= WIN_G) { rr1 = 0; wbv = 0.f; }
    s_wa[tap][n_] = wa;
    s_wb[tap][n_] = wbv;
    s_r01[tap][n_] = (unsigned)rr0 | ((unsigned)rr1 << 8);
  }
  __syncthreads();

  int lane = t & 63, ng = t >> 6;
  int qk = lane >> 4, hrow = lane & 15;
  int n = ng * 16 + hrow;

  float4v acc[8];
  #pragma unroll
  for (int i = 0; i < 8; ++i) acc[i] = (float4v){0.f, 0.f, 0.f, 0.f};

  const short* wpb = Wp2 + qk * 1024 + hrow * 8;

  #pragma unroll
  for (int kt = 0; kt < 3; ++kt) {
    float wa = s_wa[kt][n];
    float wbv = s_wb[kt][n];
    unsigned r01 = s_r01[kt][n];
    int r0 = r01 & 0xff, r1 = (r01 >> 8) & 0xff;
    int b0 = r0 * 256, m0 = r0 & 15;
    int b1 = r1 * 256, m1 = r1 & 15;
    #pragma unroll
    for (int s = 0; s < 4; ++s) {
      int ks = kt * 4 + s;
      int ch = qk * 4 + s;
      uint4 q0 = *(const uint4*)(xsb + b0 + ((ch ^ m0) << 4));
      uint4 q1 = *(const uint4*)(xsb + b1 + ((ch ^ m1) << 4));
      const unsigned* q0u = (const unsigned*)&q0;
      const unsigned* q1u = (const unsigned*)&q1;
      union { unsigned u[4]; short8 s8; } bu;
      #pragma unroll
      for (int j = 0; j < 4; ++j) {
        float glo = wa * bflo(q0u[j]) + wbv * bflo(q1u[j]);
        float ghi = wa * bfhi(q0u[j]) + wbv * bfhi(q1u[j]);
        bu.u[j] = packbf(glo, ghi);
      }
      const short* wk = wpb + ks * 4096;
      #pragma unroll
      for (int mt = 0; mt < 8; ++mt) {
        short8 a = *(const short8*)(wk + mt * 128);
        acc[mt] = __builtin_amdgcn_mfma_f32_16x16x32_bf16(a, bu.s8, acc[mt], 0, 0, 0);
      }
    }
  }

  // epilogue: C/D col=lane&15 (n), row=qk*4+reg (within 16-row m-tile)
  float* ob = out + (size_t)b * C_CH * L_LEN + l0 + n;
  #pragma unroll
  for (int mt = 0; mt < 8; ++mt) {
    int o = mt * 16 + qk * 4;
    #pragma unroll
    for (int r = 0; r < 4; ++r) {
      ob[(size_t)(o + r) * L_LEN] = acc[mt][r];
    }
  }
}

extern "C" void kernel_launch(void* const* d_in, const int* in_sizes, int n_in,
                              void* d_out, int out_size, void* d_ws, size_t ws_size,
                              hipStream_t stream) {
  const float* x    = (const float*)d_in[0];
  const float* dw_w = (const float*)d_in[1];
  const float* dw_b = (const float*)d_in[2];
  const float* ln_g = (const float*)d_in[3];
  const float* ln_b = (const float*)d_in[4];
  const float* off_w = (const float*)d_in[5];
  const float* off_b = (const float*)d_in[6];
  const float* dc_w = (const float*)d_in[7];
  float* out = (float*)d_out;

  char* ws = (char*)d_ws;
  short* Wp2 = (short*)ws;                                   // 96 KB
  const size_t DSZ = (size_t)B_N * K_T * L_LEN * 4;          // 1.5 MB each
  float* d_wa = (float*)(ws + 0x40000);
  float* d_wb = (float*)(ws + 0x40000 + DSZ);
  unsigned* d_idx = (unsigned*)(ws + 0x40000 + 2 * DSZ);

  hipLaunchKernelGGL(repack_w2, dim3(192), dim3(256), 0, stream, dc_w, Wp2);
  hipLaunchKernelGGL(offsets_k2, dim3(L_LEN / 128, B_N), dim3(512), 0, stream,
                     x, dw_w, dw_b, ln_g, ln_b, off_w, off_b, d_wa, d_wb, d_idx);
  hipLaunchKernelGGL(deform_gemm2, dim3(L_LEN / 64, B_N), dim3(256), 0, stream,
                     x, d_wa, d_wb, d_idx, Wp2, out);
}

// Round 5
// 191.035 us; speedup vs baseline: 1.4327x; 1.4327x over previous
//
#include <hip/hip_runtime.h>
#include <hip/hip_bf16.h>
#include <cstdint>
#include <cstddef>

#define C_CH 128
#define L_LEN 16384
#define B_N 8
#define K_T 3
#define EPS 1e-5f
#define WPAD 8
#define WIN_G 144   // kernel G window rows: 128-l tile + 2*8

typedef __attribute__((ext_vector_type(8))) short short8;
typedef __attribute__((ext_vector_type(4))) float float4v;

__device__ __forceinline__ short f2bf(float f) {
  union { float f; unsigned u; } v; v.f = f;
  unsigned r = v.u + 0x7fffu + ((v.u >> 16) & 1u);
  return (short)(r >> 16);
}
__device__ __forceinline__ float bflo(unsigned d) {
  union { unsigned u; float f; } v; v.u = d << 16; return v.f;
}
__device__ __forceinline__ float bfhi(unsigned d) {
  union { unsigned u; float f; } v; v.u = d & 0xffff0000u; return v.f;
}
__device__ __forceinline__ unsigned packbf(float a, float b) {
  unsigned ua = __float_as_uint(a) + 0x8000u;
  unsigned ub = __float_as_uint(b) + 0x8000u;
  return (ua >> 16) | (ub & 0xffff0000u);
}
__device__ __forceinline__ int clampL(int v) {
  return v < 0 ? 0 : (v > L_LEN - 1 ? L_LEN - 1 : v);
}
// async global->LDS, 16 B per lane; LDS dst = wave-uniform base + lane*16
__device__ __forceinline__ void gl_lds16(const void* g, void* l) {
  __builtin_amdgcn_global_load_lds(
      (const __attribute__((address_space(1))) unsigned*)g,
      (__attribute__((address_space(3))) unsigned*)l, 16, 0, 0);
}

// ---- repack dc_w [m][c][kt] f32 -> Wp2 bf16, linear = ((ks*4+qk)*128 + m)*8 + j,
// A[m][k=ks*32+qk*8+j] = dcw[m][c][kt], c = qk*32 + (ks&3)*8 + j, kt = ks>>2.
__global__ void repack_w2(const float* __restrict__ dc_w, short* __restrict__ Wp2) {
  int tid = blockIdx.x * 256 + threadIdx.x;
  if (tid >= C_CH * C_CH * K_T) return;
  int j = tid & 7;
  int m = (tid >> 3) & 127;
  int qk = (tid >> 10) & 3;
  int ks = tid >> 12;
  int kt = ks >> 2, s = ks & 3;
  int c = qk * 32 + s * 8 + j;
  Wp2[tid] = f2bf(dc_w[(m * C_CH + c) * K_T + kt]);
}

// ---- Kernel O: one pass over x. thread=(l, sub): y for 32 channels in registers,
// dwconv+LN+ReLU+offset linear; ALSO writes xT = bf16 [b][l][c] (coalesced 16B stores).
__global__ __launch_bounds__(256, 4) void offsets_k3(
    const float* __restrict__ x,
    const float* __restrict__ dw_w, const float* __restrict__ dw_b,
    const float* __restrict__ ln_g, const float* __restrict__ ln_b,
    const float* __restrict__ off_w, const float* __restrict__ off_b,
    short* __restrict__ xT, unsigned* __restrict__ d_wab, unsigned* __restrict__ d_idx) {
  __shared__ float swt[1152];   // dw_w[384] dw_b[128] ln_g[128] ln_b[128] off_w[384]
  int t = threadIdx.x;
  int b = blockIdx.y;
  int l0 = blockIdx.x * 64;

  for (int i = t; i < 1152; i += 256) {
    float v;
    if (i < 384) v = dw_w[i];
    else if (i < 512) v = dw_b[i - 384];
    else if (i < 640) v = ln_g[i - 512];
    else if (i < 768) v = ln_b[i - 640];
    else v = off_w[i - 768];
    swt[i] = v;
  }
  __syncthreads();

  int l_loc = t >> 2, sub = t & 3;
  int lg = l0 + l_loc;
  float mL = (lg >= 1) ? 1.f : 0.f;
  float mR = (lg + 1 < L_LEN) ? 1.f : 0.f;
  int lgm = lg - 1 < 0 ? 0 : lg - 1;
  int lgp = lg + 1 > L_LEN - 1 ? L_LEN - 1 : lg + 1;
  const float* xb = x + (size_t)b * C_CH * L_LEN;
  const float* xc = xb + (size_t)(sub * 32) * L_LEN;

  float ys[32];
  unsigned xpk[16];
  float sum = 0.f, sumsq = 0.f;
  #pragma unroll
  for (int j = 0; j < 32; ++j) {
    const float* xr = xc + (size_t)j * L_LEN;
    float xm = xr[lgm], x0 = xr[lg], xp = xr[lgp];
    int c = sub * 32 + j;
    float y = swt[384 + c] + mL * xm * swt[3 * c] + x0 * swt[3 * c + 1] + mR * xp * swt[3 * c + 2];
    ys[j] = y;
    sum += y;
    sumsq += y * y;
    unsigned ub = __float_as_uint(x0) + 0x8000u;
    if (j & 1) xpk[j >> 1] |= ub & 0xffff0000u;
    else       xpk[j >> 1]  = ub >> 16;
  }
  // xT[b][l][c] bf16: thread writes its 32 channels (64 B contiguous)
  {
    short* xtp = xT + ((size_t)(b * L_LEN + lg) * C_CH + sub * 32);
    #pragma unroll
    for (int q4 = 0; q4 < 4; ++q4) {
      uint4 q;
      q.x = xpk[q4 * 4]; q.y = xpk[q4 * 4 + 1]; q.z = xpk[q4 * 4 + 2]; q.w = xpk[q4 * 4 + 3];
      *(uint4*)(xtp + q4 * 8) = q;
    }
  }
  sum += __shfl_xor(sum, 1, 64);     sum += __shfl_xor(sum, 2, 64);
  sumsq += __shfl_xor(sumsq, 1, 64); sumsq += __shfl_xor(sumsq, 2, 64);
  float mean = sum * (1.f / C_CH);
  float var = sumsq * (1.f / C_CH) - mean * mean;
  float rstd = rsqrtf(var + EPS);

  float o0 = 0.f, o1 = 0.f, o2 = 0.f;
  #pragma unroll
  for (int j = 0; j < 32; ++j) {
    int c = sub * 32 + j;
    float yn = (ys[j] - mean) * rstd * swt[512 + c] + swt[640 + c];
    float yr = yn > 0.f ? yn : 0.f;
    o0 += yr * swt[768 + c];
    o1 += yr * swt[896 + c];
    o2 += yr * swt[1024 + c];
  }
  o0 += __shfl_xor(o0, 1, 64); o0 += __shfl_xor(o0, 2, 64);
  o1 += __shfl_xor(o1, 1, 64); o1 += __shfl_xor(o1, 2, 64);
  o2 += __shfl_xor(o2, 1, 64); o2 += __shfl_xor(o2, 2, 64);

  if (sub < 3) {
    float o = (sub == 0 ? o0 : (sub == 1 ? o1 : o2)) + off_b[sub];
    float pos = (float)(lg + sub - 1) + o;
    float p0f = floorf(pos);
    float fr = pos - p0f;
    int i0 = (int)p0f, i1 = i0 + 1;
    float wa = (i0 >= 0 && i0 < L_LEN) ? (1.f - fr) : 0.f;
    float wbv = (i1 >= 0 && i1 < L_LEN) ? fr : 0.f;
    int i0c = clampL(i0), i1c = clampL(i1);
    size_t di = ((size_t)b * K_T + sub) * L_LEN + lg;
    d_wab[di] = packbf(wa, wbv);
    d_idx[di] = (unsigned)i0c | ((unsigned)i1c << 16);
  }
}

// ---- Kernel G: deform GEMM. Block 256 thr (4 waves), tile M=128 x N=128.
// Wave wv covers cols [wv*32, wv*32+32) (2 MFMA subtiles). Window staged from xT via
// global_load_lds dwordx4 (lane-linear LDS); XOR swizzle applied on the GLOBAL address:
// LDS row r slot s holds global chunk (s ^ (r&15)) of 8 channels.
__global__ __launch_bounds__(256, 4) void deform_gemm3(
    const short* __restrict__ xT,
    const unsigned* __restrict__ d_wab, const unsigned* __restrict__ d_idx,
    const short* __restrict__ Wp2, float* __restrict__ out) {
  __shared__ short xs[WIN_G * 128];        // 36864 B
  __shared__ unsigned s_wab[K_T][128];     // wa|wb bf16-packed
  __shared__ unsigned s_r01[K_T][128];     // r0 | r1<<16 window-relative

  int t = threadIdx.x;
  int b = blockIdx.y;
  int l0 = blockIdx.x * 128;
  int wb0 = l0 - WPAD;
  int lane = t & 63, wv = t >> 6;
  int qk = lane >> 4, hrow = lane & 15;

  // stage window: wave wv stages rows [wv*36, wv*36+36), 4 rows per instruction
  const short* xTb = xT + (size_t)b * L_LEN * C_CH;
  #pragma unroll
  for (int i = 0; i < 9; ++i) {
    int rb = wv * 36 + i * 4;
    int r = rb + (lane >> 4);
    int lrow = clampL(wb0 + r);
    int slot = lane & 15;
    const short* g = xTb + (size_t)lrow * C_CH + ((slot ^ (r & 15)) << 3);
    gl_lds16(g, &xs[rb * 128]);
  }

  // descriptors -> window-relative (384 of them)
  for (int d = t; d < 384; d += 256) {
    int n = d & 127, tap = d >> 7;
    size_t di = ((size_t)b * K_T + tap) * L_LEN + (l0 + n);
    unsigned wab = d_wab[di];
    unsigned ii = d_idx[di];
    int r0 = (int)(ii & 0xffffu) - wb0;
    int r1 = (int)(ii >> 16) - wb0;
    if ((unsigned)r0 >= WIN_G) { r0 = 0; wab &= 0xffff0000u; }  // zero wa
    if ((unsigned)r1 >= WIN_G) { r1 = 0; wab &= 0x0000ffffu; }  // zero wb
    s_wab[tap][n] = wab;
    s_r01[tap][n] = (unsigned)r0 | ((unsigned)r1 << 16);
  }
  __syncthreads();

  float4v acc[8][2];
  #pragma unroll
  for (int i = 0; i < 8; ++i) {
    acc[i][0] = (float4v){0.f, 0.f, 0.f, 0.f};
    acc[i][1] = (float4v){0.f, 0.f, 0.f, 0.f};
  }
  const short* wpb = Wp2 + qk * 1024 + hrow * 8;
  const char* xsb = (const char*)xs;

  #pragma unroll
  for (int kt = 0; kt < 3; ++kt) {
    float wa[2], wbv[2];
    int b0[2], m0_[2], b1[2], m1_[2];
    #pragma unroll
    for (int nt = 0; nt < 2; ++nt) {
      int n = wv * 32 + nt * 16 + hrow;
      unsigned wab = s_wab[kt][n];
      wa[nt] = bflo(wab);
      wbv[nt] = bfhi(wab);
      unsigned r01 = s_r01[kt][n];
      int r0 = r01 & 0xffff, r1 = r01 >> 16;
      b0[nt] = r0 * 256; m0_[nt] = r0 & 15;
      b1[nt] = r1 * 256; m1_[nt] = r1 & 15;
    }
    #pragma unroll
    for (int s = 0; s < 4; ++s) {
      int ks = kt * 4 + s;
      int ch = qk * 4 + s;
      short8 bfrag[2];
      #pragma unroll
      for (int nt = 0; nt < 2; ++nt) {
        uint4 q0 = *(const uint4*)(xsb + b0[nt] + ((ch ^ m0_[nt]) << 4));
        uint4 q1 = *(const uint4*)(xsb + b1[nt] + ((ch ^ m1_[nt]) << 4));
        const unsigned* q0u = (const unsigned*)&q0;
        const unsigned* q1u = (const unsigned*)&q1;
        union { unsigned u[4]; short8 s8; } bu;
        #pragma unroll
        for (int j = 0; j < 4; ++j) {
          float glo = wa[nt] * bflo(q0u[j]) + wbv[nt] * bflo(q1u[j]);
          float ghi = wa[nt] * bfhi(q0u[j]) + wbv[nt] * bfhi(q1u[j]);
          bu.u[j] = packbf(glo, ghi);
        }
        bfrag[nt] = bu.s8;
      }
      const short* wk = wpb + ks * 4096;
      #pragma unroll
      for (int mt = 0; mt < 8; ++mt) {
        short8 a = *(const short8*)(wk + mt * 128);
        acc[mt][0] = __builtin_amdgcn_mfma_f32_16x16x32_bf16(a, bfrag[0], acc[mt][0], 0, 0, 0);
        acc[mt][1] = __builtin_amdgcn_mfma_f32_16x16x32_bf16(a, bfrag[1], acc[mt][1], 0, 0, 0);
      }
    }
  }

  // epilogue: C/D col=lane&15, row=(lane>>4)*4+reg within each 16-row m-tile
  float* ob = out + (size_t)b * C_CH * L_LEN + l0;
  #pragma unroll
  for (int mt = 0; mt < 8; ++mt) {
    #pragma unroll
    for (int nt = 0; nt < 2; ++nt) {
      int col = wv * 32 + nt * 16 + hrow;
      #pragma unroll
      for (int r = 0; r < 4; ++r) {
        ob[(size_t)(mt * 16 + qk * 4 + r) * L_LEN + col] = acc[mt][nt][r];
      }
    }
  }
}

extern "C" void kernel_launch(void* const* d_in, const int* in_sizes, int n_in,
                              void* d_out, int out_size, void* d_ws, size_t ws_size,
                              hipStream_t stream) {
  const float* x    = (const float*)d_in[0];
  const float* dw_w = (const float*)d_in[1];
  const float* dw_b = (const float*)d_in[2];
  const float* ln_g = (const float*)d_in[3];
  const float* ln_b = (const float*)d_in[4];
  const float* off_w = (const float*)d_in[5];
  const float* off_b = (const float*)d_in[6];
  const float* dc_w = (const float*)d_in[7];
  float* out = (float*)d_out;

  char* ws = (char*)d_ws;
  short* xT = (short*)ws;                                  // 33,554,432 B
  short* Wp2 = (short*)(ws + 0x2000000);                   // 98,304 B
  unsigned* d_wab = (unsigned*)(ws + 0x2018000);           // 1.5 MB
  unsigned* d_idx = (unsigned*)(ws + 0x2198000);           // 1.5 MB

  hipLaunchKernelGGL(repack_w2, dim3(192), dim3(256), 0, stream, dc_w, Wp2);
  hipLaunchKernelGGL(offsets_k3, dim3(L_LEN / 64, B_N), dim3(256), 0, stream,
                     x, dw_w, dw_b, ln_g, ln_b, off_w, off_b, xT, d_wab, d_idx);
  hipLaunchKernelGGL(deform_gemm3, dim3(L_LEN / 128, B_N), dim3(256), 0, stream,
                     xT, d_wab, d_idx, Wp2, out);
}

// Round 6
// 189.517 us; speedup vs baseline: 1.4442x; 1.0080x over previous
//
#include <hip/hip_runtime.h>
#include <hip/hip_bf16.h>
#include <cstdint>
#include <cstddef>

#define C_CH 128
#define L_LEN 16384
#define B_N 8
#define K_T 3
#define EPS 1e-5f
#define WPAD 8
#define WIN_G 144   // gemm window rows: 128-l tile + 2*8
#define WIN_O 132   // offsets window rows: 128-l tile + halo (l = l0-2+r, need l0-1..l0+128)

typedef __attribute__((ext_vector_type(8))) short short8;
typedef __attribute__((ext_vector_type(4))) float float4v;

__device__ __forceinline__ short f2bf(float f) {
  union { float f; unsigned u; } v; v.f = f;
  unsigned r = v.u + 0x7fffu + ((v.u >> 16) & 1u);
  return (short)(r >> 16);
}
__device__ __forceinline__ float bflo(unsigned d) {
  union { unsigned u; float f; } v; v.u = d << 16; return v.f;
}
__device__ __forceinline__ float bfhi(unsigned d) {
  union { unsigned u; float f; } v; v.u = d & 0xffff0000u; return v.f;
}
__device__ __forceinline__ unsigned packbf(float a, float b) {
  unsigned ua = __float_as_uint(a) + 0x8000u;
  unsigned ub = __float_as_uint(b) + 0x8000u;
  return (ua >> 16) | (ub & 0xffff0000u);
}
__device__ __forceinline__ int clampL(int v) {
  return v < 0 ? 0 : (v > L_LEN - 1 ? L_LEN - 1 : v);
}
__device__ __forceinline__ void gl_lds16(const void* g, void* l) {
  __builtin_amdgcn_global_load_lds(
      (const __attribute__((address_space(1))) unsigned*)g,
      (__attribute__((address_space(3))) unsigned*)l, 16, 0, 0);
}

// ---- repack dc_w [m][c][kt] f32 -> Wp2 bf16, linear = ((ks*4+qk)*128 + m)*8 + j,
// A[m][k=ks*32+qk*8+j] = dcw[m][c][kt], c = qk*32 + (ks&3)*8 + j, kt = ks>>2.
__global__ void repack_w2(const float* __restrict__ dc_w, short* __restrict__ Wp2) {
  int tid = blockIdx.x * 256 + threadIdx.x;
  if (tid >= C_CH * C_CH * K_T) return;
  int j = tid & 7;
  int m = (tid >> 3) & 127;
  int qk = (tid >> 10) & 3;
  int ks = tid >> 12;
  int kt = ks >> 2, s = ks & 3;
  int c = qk * 32 + s * 8 + j;
  Wp2[tid] = f2bf(dc_w[(m * C_CH + c) * K_T + kt]);
}

// ---- Kernel O v4: coalesced LDS staging of x tile -> xT writeback + dwconv/LN/ReLU/linear.
// LDS tile: row r (l = l0-2+r), 16 chunks of 8 bf16 channels, chunk ch at slot (ch ^ (r&15)).
__global__ __launch_bounds__(256, 4) void offsets_k4(
    const float* __restrict__ x,
    const float* __restrict__ dw_w, const float* __restrict__ dw_b,
    const float* __restrict__ ln_g, const float* __restrict__ ln_b,
    const float* __restrict__ off_w, const float* __restrict__ off_b,
    short* __restrict__ xT, unsigned* __restrict__ d_wab, unsigned* __restrict__ d_idx) {
  __shared__ short xs[WIN_O * 128];   // 33792 B
  __shared__ float swt[1152];         // dw_w[384] dw_b[128] ln_g[128] ln_b[128] off_w[384]

  int t = threadIdx.x;
  int b = blockIdx.y;
  int l0 = blockIdx.x * 128;
  const float* xb = x + (size_t)b * C_CH * L_LEN;
  char* xsb = (char*)xs;

  for (int i = t; i < 1152; i += 256) {
    float v;
    if (i < 384) v = dw_w[i];
    else if (i < 512) v = dw_b[i - 384];
    else if (i < 640) v = ln_g[i - 512];
    else if (i < 768) v = ln_b[i - 640];
    else v = off_w[i - 768];
    swt[i] = v;
  }

  int lane = t & 63, wv = t >> 6;

  // ---- phase A: stage x -> LDS. task (cc, lq): 8 channel rows x 4 l, coalesced float4 loads.
  {
    int cc = wv * 4 + (lane >> 4);    // chunk 0..15
    int lqi = lane & 15;
    #pragma unroll
    for (int i = 0; i < 3; ++i) {
      int lq = i * 16 + lqi;
      if (lq < 33) {
        int bl = l0 - 2 + lq * 4;
        float fv[8][4];
        if (bl >= 0 && bl + 3 <= L_LEN - 1) {
          #pragma unroll
          for (int j = 0; j < 8; ++j) {
            float4 f = *(const float4*)(xb + (size_t)(cc * 8 + j) * L_LEN + bl);
            fv[j][0] = f.x; fv[j][1] = f.y; fv[j][2] = f.z; fv[j][3] = f.w;
          }
        } else {
          #pragma unroll
          for (int j = 0; j < 8; ++j)
            #pragma unroll
            for (int k = 0; k < 4; ++k)
              fv[j][k] = xb[(size_t)(cc * 8 + j) * L_LEN + clampL(bl + k)];
        }
        #pragma unroll
        for (int k = 0; k < 4; ++k) {
          int rr = lq * 4 + k;
          uint4 q;
          q.x = packbf(fv[0][k], fv[1][k]);
          q.y = packbf(fv[2][k], fv[3][k]);
          q.z = packbf(fv[4][k], fv[5][k]);
          q.w = packbf(fv[6][k], fv[7][k]);
          *(uint4*)(xsb + rr * 256 + ((cc ^ (rr & 15)) << 4)) = q;
        }
      }
    }
  }
  __syncthreads();

  // ---- phase C: xT writeback (LDS -> global, 1 KB contiguous per wave instruction)
  {
    short* xTb = xT + (size_t)b * L_LEN * C_CH;
    int sg = lane & 15;
    int rbase = wv * 4 + (lane >> 4);   // 0..15 unique
    #pragma unroll
    for (int i = 0; i < 8; ++i) {
      int lr = rbase + i * 16;
      int r = lr + 2;
      uint4 q = *(const uint4*)(xsb + r * 256 + ((sg ^ (r & 15)) << 4));
      *(uint4*)(xTb + (size_t)(l0 + lr) * C_CH + sg * 8) = q;
    }
  }

  // ---- phase B: dwconv + LN + ReLU + offset linear (x from LDS, ys in registers)
  #pragma unroll
  for (int it = 0; it < 2; ++it) {
    int l_loc = (t >> 2) + it * 64;
    int sub = t & 3;
    int lg = l0 + l_loc;
    float mL = (lg >= 1) ? 1.f : 0.f;
    float mR = (lg + 1 < L_LEN) ? 1.f : 0.f;
    int rm = l_loc + 2;

    float ys[32];
    float sum = 0.f, sumsq = 0.f;
    #pragma unroll
    for (int oct = 0; oct < 4; ++oct) {
      int ch = sub * 4 + oct;
      int r0 = rm - 1, r1 = rm, r2 = rm + 1;
      uint4 q0 = *(const uint4*)(xsb + r0 * 256 + ((ch ^ (r0 & 15)) << 4));
      uint4 q1 = *(const uint4*)(xsb + r1 * 256 + ((ch ^ (r1 & 15)) << 4));
      uint4 q2 = *(const uint4*)(xsb + r2 * 256 + ((ch ^ (r2 & 15)) << 4));
      const unsigned* u0 = (const unsigned*)&q0;
      const unsigned* u1 = (const unsigned*)&q1;
      const unsigned* u2 = (const unsigned*)&q2;
      #pragma unroll
      for (int j = 0; j < 4; ++j) {
        int c = ch * 8 + 2 * j;
        float y0 = swt[384 + c] + mL * bflo(u0[j]) * swt[3 * c]
                 + bflo(u1[j]) * swt[3 * c + 1] + mR * bflo(u2[j]) * swt[3 * c + 2];
        float y1 = swt[385 + c] + mL * bfhi(u0[j]) * swt[3 * c + 3]
                 + bfhi(u1[j]) * swt[3 * c + 4] + mR * bfhi(u2[j]) * swt[3 * c + 5];
        ys[oct * 8 + 2 * j] = y0;
        ys[oct * 8 + 2 * j + 1] = y1;
        sum += y0 + y1;
        sumsq += y0 * y0 + y1 * y1;
      }
    }
    sum += __shfl_xor(sum, 1, 64);     sum += __shfl_xor(sum, 2, 64);
    sumsq += __shfl_xor(sumsq, 1, 64); sumsq += __shfl_xor(sumsq, 2, 64);
    float mean = sum * (1.f / C_CH);
    float var = sumsq * (1.f / C_CH) - mean * mean;
    float rstd = rsqrtf(var + EPS);

    float o0 = 0.f, o1 = 0.f, o2 = 0.f;
    #pragma unroll
    for (int li = 0; li < 32; ++li) {
      int c = sub * 32 + li;
      float yn = (ys[li] - mean) * rstd * swt[512 + c] + swt[640 + c];
      float yr = yn > 0.f ? yn : 0.f;
      o0 += yr * swt[768 + c];
      o1 += yr * swt[896 + c];
      o2 += yr * swt[1024 + c];
    }
    o0 += __shfl_xor(o0, 1, 64); o0 += __shfl_xor(o0, 2, 64);
    o1 += __shfl_xor(o1, 1, 64); o1 += __shfl_xor(o1, 2, 64);
    o2 += __shfl_xor(o2, 1, 64); o2 += __shfl_xor(o2, 2, 64);

    if (sub < 3) {
      float o = (sub == 0 ? o0 : (sub == 1 ? o1 : o2)) + off_b[sub];
      float pos = (float)(lg + sub - 1) + o;
      float p0f = floorf(pos);
      float fr = pos - p0f;
      int i0 = (int)p0f, i1 = i0 + 1;
      float wa = (i0 >= 0 && i0 < L_LEN) ? (1.f - fr) : 0.f;
      float wbv = (i1 >= 0 && i1 < L_LEN) ? fr : 0.f;
      int i0c = clampL(i0), i1c = clampL(i1);
      size_t di = ((size_t)b * K_T + sub) * L_LEN + lg;
      d_wab[di] = packbf(wa, wbv);
      d_idx[di] = (unsigned)i0c | ((unsigned)i1c << 16);
    }
  }
}

// ---- Kernel G: deform GEMM (unchanged from R5). Block 256 thr, tile M=128 x N=128.
__global__ __launch_bounds__(256, 4) void deform_gemm3(
    const short* __restrict__ xT,
    const unsigned* __restrict__ d_wab, const unsigned* __restrict__ d_idx,
    const short* __restrict__ Wp2, float* __restrict__ out) {
  __shared__ short xs[WIN_G * 128];        // 36864 B
  __shared__ unsigned s_wab[K_T][128];
  __shared__ unsigned s_r01[K_T][128];

  int t = threadIdx.x;
  int b = blockIdx.y;
  int l0 = blockIdx.x * 128;
  int wb0 = l0 - WPAD;
  int lane = t & 63, wv = t >> 6;
  int qk = lane >> 4, hrow = lane & 15;

  const short* xTb = xT + (size_t)b * L_LEN * C_CH;
  #pragma unroll
  for (int i = 0; i < 9; ++i) {
    int rb = wv * 36 + i * 4;
    int r = rb + (lane >> 4);
    int lrow = clampL(wb0 + r);
    int slot = lane & 15;
    const short* g = xTb + (size_t)lrow * C_CH + ((slot ^ (r & 15)) << 3);
    gl_lds16(g, &xs[rb * 128]);
  }

  for (int d = t; d < 384; d += 256) {
    int n = d & 127, tap = d >> 7;
    size_t di = ((size_t)b * K_T + tap) * L_LEN + (l0 + n);
    unsigned wab = d_wab[di];
    unsigned ii = d_idx[di];
    int r0 = (int)(ii & 0xffffu) - wb0;
    int r1 = (int)(ii >> 16) - wb0;
    if ((unsigned)r0 >= WIN_G) { r0 = 0; wab &= 0xffff0000u; }
    if ((unsigned)r1 >= WIN_G) { r1 = 0; wab &= 0x0000ffffu; }
    s_wab[tap][n] = wab;
    s_r01[tap][n] = (unsigned)r0 | ((unsigned)r1 << 16);
  }
  __syncthreads();

  float4v acc[8][2];
  #pragma unroll
  for (int i = 0; i < 8; ++i) {
    acc[i][0] = (float4v){0.f, 0.f, 0.f, 0.f};
    acc[i][1] = (float4v){0.f, 0.f, 0.f, 0.f};
  }
  const short* wpb = Wp2 + qk * 1024 + hrow * 8;
  const char* xsb = (const char*)xs;

  #pragma unroll
  for (int kt = 0; kt < 3; ++kt) {
    float wa[2], wbv[2];
    int b0[2], m0_[2], b1[2], m1_[2];
    #pragma unroll
    for (int nt = 0; nt < 2; ++nt) {
      int n = wv * 32 + nt * 16 + hrow;
      unsigned wab = s_wab[kt][n];
      wa[nt] = bflo(wab);
      wbv[nt] = bfhi(wab);
      unsigned r01 = s_r01[kt][n];
      int r0 = r01 & 0xffff, r1 = r01 >> 16;
      b0[nt] = r0 * 256; m0_[nt] = r0 & 15;
      b1[nt] = r1 * 256; m1_[nt] = r1 & 15;
    }
    #pragma unroll
    for (int s = 0; s < 4; ++s) {
      int ks = kt * 4 + s;
      int ch = qk * 4 + s;
      short8 bfrag[2];
      #pragma unroll
      for (int nt = 0; nt < 2; ++nt) {
        uint4 q0 = *(const uint4*)(xsb + b0[nt] + ((ch ^ m0_[nt]) << 4));
        uint4 q1 = *(const uint4*)(xsb + b1[nt] + ((ch ^ m1_[nt]) << 4));
        const unsigned* q0u = (const unsigned*)&q0;
        const unsigned* q1u = (const unsigned*)&q1;
        union { unsigned u[4]; short8 s8; } bu;
        #pragma unroll
        for (int j = 0; j < 4; ++j) {
          float glo = wa[nt] * bflo(q0u[j]) + wbv[nt] * bflo(q1u[j]);
          float ghi = wa[nt] * bfhi(q0u[j]) + wbv[nt] * bfhi(q1u[j]);
          bu.u[j] = packbf(glo, ghi);
        }
        bfrag[nt] = bu.s8;
      }
      const short* wk = wpb + ks * 4096;
      #pragma unroll
      for (int mt = 0; mt < 8; ++mt) {
        short8 a = *(const short8*)(wk + mt * 128);
        acc[mt][0] = __builtin_amdgcn_mfma_f32_16x16x32_bf16(a, bfrag[0], acc[mt][0], 0, 0, 0);
        acc[mt][1] = __builtin_amdgcn_mfma_f32_16x16x32_bf16(a, bfrag[1], acc[mt][1], 0, 0, 0);
      }
    }
  }

  float* ob = out + (size_t)b * C_CH * L_LEN + l0;
  #pragma unroll
  for (int mt = 0; mt < 8; ++mt) {
    #pragma unroll
    for (int nt = 0; nt < 2; ++nt) {
      int col = wv * 32 + nt * 16 + hrow;
      #pragma unroll
      for (int r = 0; r < 4; ++r) {
        ob[(size_t)(mt * 16 + qk * 4 + r) * L_LEN + col] = acc[mt][nt][r];
      }
    }
  }
}

extern "C" void kernel_launch(void* const* d_in, const int* in_sizes, int n_in,
                              void* d_out, int out_size, void* d_ws, size_t ws_size,
                              hipStream_t stream) {
  const float* x    = (const float*)d_in[0];
  const float* dw_w = (const float*)d_in[1];
  const float* dw_b = (const float*)d_in[2];
  const float* ln_g = (const float*)d_in[3];
  const float* ln_b = (const float*)d_in[4];
  const float* off_w = (const float*)d_in[5];
  const float* off_b = (const float*)d_in[6];
  const float* dc_w = (const float*)d_in[7];
  float* out = (float*)d_out;

  char* ws = (char*)d_ws;
  short* xT = (short*)ws;                                  // 33,554,432 B
  short* Wp2 = (short*)(ws + 0x2000000);                   // 98,304 B
  unsigned* d_wab = (unsigned*)(ws + 0x2018000);           // 1.5 MB
  unsigned* d_idx = (unsigned*)(ws + 0x2198000);           // 1.5 MB

  hipLaunchKernelGGL(repack_w2, dim3(192), dim3(256), 0, stream, dc_w, Wp2);
  hipLaunchKernelGGL(offsets_k4, dim3(L_LEN / 128, B_N), dim3(256), 0, stream,
                     x, dw_w, dw_b, ln_g, ln_b, off_w, off_b, xT, d_wab, d_idx);
  hipLaunchKernelGGL(deform_gemm3, dim3(L_LEN / 128, B_N), dim3(256), 0, stream,
                     xT, d_wab, d_idx, Wp2, out);
}